// Round 4
// baseline (152.605 us; speedup 1.0000x reference)
//
#include <hip/hip_runtime.h>

// 21-qubit HEA, fp32, all-real. SINGLE fused kernel: three phases (R3's
// verified k1/k2/k3 bodies) separated by device-scope grid barriers.
// 256 blocks x 256 threads = 1 block/CU on 256 CUs -> all blocks co-resident,
// manual grid sync is safe. Barrier counters live in d_ws at +32 MiB and are
// zeroed by a hipMemsetAsync node before the kernel (re-runs on every graph
// replay). qubit q <-> index bit (20-q). Params: RY1 q->p[q], RY2 q->p[21+q],
// RY3 q->p[42+q]. Chain C_k = CNOT(q_k,q_{k+1}) in order. Norm==1 (unitary).
//
// Init (layer1+chain1) closed form: amp(x) = prod_b f_{20-b}(y_b),
// y_b = x_b ^ x_{b+1} (local Gray decode).

#define NQ 21
#define NSTATE (1 << NQ)
#define NBLK 256
#define BAR_OFF (32u << 20)  // byte offset of barrier counters in d_ws
#define SW(t) ((t) + ((t) >> 5))  // LDS anti-conflict: +1 word per 32 words

__device__ __forceinline__ float sel(const float* cs, const float* sn, int i,
                                     int bit) {
  return bit ? sn[i] : cs[i];
}

template <int BIT, int N>
__device__ __forceinline__ void ry_bf(float (&v)[N], float c, float s) {
#pragma unroll
  for (int m = 0; m < N; ++m)
    if ((m & (1 << BIT)) == 0) {
      float a = v[m], b = v[m | (1 << BIT)];
      v[m] = c * a - s * b;
      v[m | (1 << BIT)] = s * a + c * b;
    }
}

template <int CBIT, int TBIT, int N>
__device__ __forceinline__ void cnot_rr(float (&v)[N]) {
#pragma unroll
  for (int m = 0; m < N; ++m)
    if ((m & (1 << CBIT)) && !(m & (1 << TBIT))) {
      float t = v[m];
      v[m] = v[m | (1 << TBIT)];
      v[m | (1 << TBIT)] = t;
    }
}

// Device-scope grid barrier: one counter per use, pre-zeroed by memset node.
__device__ __forceinline__ void grid_sync(unsigned* bar) {
  __syncthreads();
  if (threadIdx.x == 0) {
    __threadfence();  // release all prior global writes (L2 writeback)
    __hip_atomic_fetch_add(bar, 1u, __ATOMIC_ACQ_REL, __HIP_MEMORY_SCOPE_AGENT);
    while (__hip_atomic_load(bar, __ATOMIC_ACQUIRE, __HIP_MEMORY_SCOPE_AGENT) <
           NBLK) {
      __builtin_amdgcn_s_sleep(1);
    }
  }
  __syncthreads();
}

__global__ __launch_bounds__(256) void fused(const float* __restrict__ p,
                                             float* __restrict__ st,
                                             float* __restrict__ out,
                                             int outmode, unsigned* bar) {
  __shared__ float cs[63], sn[63];
  __shared__ float ex[8448];
  const int tid = threadIdx.x;
  const int bid = blockIdx.x;
  if (tid < 63) {
    float h = 0.5f * p[tid];
    cs[tid] = cosf(h);
    sn[tid] = sinf(h);
  }
  __syncthreads();

  float v[32];

  // ================= Phase 1 (R3 k1): block owns x14..x7 = bid =============
  {
    // Layout A: thr[7:2]=x20..15, thr[1:0]=x1,x0; regs r bit j = x_{2+j}.
    const int hi6 = tid >> 2;
    const int x1 = (tid >> 1) & 1, x0 = tid & 1;

    const int gh = hi6 ^ (hi6 >> 1);  // y_{15+j}, param p[5-j]
    const int gm = bid ^ (bid >> 1);  // y_{7+i} (i<7), param p[13-i]
    float Pre = sel(cs, sn, 6, ((bid >> 7) ^ hi6) & 1);  // y_14, p[6]
#pragma unroll
    for (int j = 0; j < 6; ++j) Pre *= sel(cs, sn, 5 - j, (gh >> j) & 1);
#pragma unroll
    for (int i = 0; i < 7; ++i) Pre *= sel(cs, sn, 13 - i, (gm >> i) & 1);

    // H-table over (x1,x0), parameterized by a = x2 (= r&1):
    // base = f_19(x1^a)*f_20(x0^x1), then RY2 q19 (p40) on x1, q20 (p41) on x0
    float HH[2];
#pragma unroll
    for (int a = 0; a < 2; ++a) {
      float Hm[2][2];
#pragma unroll
      for (int X1 = 0; X1 < 2; ++X1)
#pragma unroll
        for (int X0 = 0; X0 < 2; ++X0)
          Hm[X1][X0] = sel(cs, sn, 19, X1 ^ a) * sel(cs, sn, 20, X0 ^ X1);
      {
        const float c = cs[40], s = sn[40];
#pragma unroll
        for (int X0 = 0; X0 < 2; ++X0) {
          float a0 = Hm[0][X0], a1 = Hm[1][X0];
          Hm[0][X0] = c * a0 - s * a1;
          Hm[1][X0] = s * a0 + c * a1;
        }
      }
      {
        const float c = cs[41], s = sn[41];
#pragma unroll
        for (int X1 = 0; X1 < 2; ++X1) {
          float a0 = Hm[X1][0], a1 = Hm[X1][1];
          Hm[X1][0] = c * a0 - s * a1;
          Hm[X1][1] = s * a0 + c * a1;
        }
      }
      HH[a] = Hm[x1][x0];
    }

#pragma unroll
    for (int r = 0; r < 32; ++r) {
      const int gr = r ^ (r >> 1);  // y_{2+j} (j<4); y_6 = r_4 ^ bid_0
      float prod = Pre * HH[r & 1];
      prod *= sel(cs, sn, 18, gr & 1);
      prod *= sel(cs, sn, 17, (gr >> 1) & 1);
      prod *= sel(cs, sn, 16, (gr >> 2) & 1);
      prod *= sel(cs, sn, 15, (gr >> 3) & 1);
      prod *= sel(cs, sn, 14, ((gr >> 4) ^ bid) & 1);
      v[r] = prod;
    }
    // RY2 q14..q18 on reg bits 4..0 (params 35..39)
    ry_bf<4>(v, cs[35], sn[35]);
    ry_bf<3>(v, cs[36], sn[36]);
    ry_bf<2>(v, cs[37], sn[37]);
    ry_bf<1>(v, cs[38], sn[38]);
    ry_bf<0>(v, cs[39], sn[39]);

    // Exchange A -> B. Tile t[12:7]=x20..15, t[6:0]=x6..0.
#pragma unroll
    for (int r = 0; r < 32; ++r)
      ex[SW((hi6 << 7) | (r << 2) | (tid & 3))] = v[r];
    __syncthreads();
    // Layout B: regs bit j = x_{16+j}; thr bit7=x15, bits6..0=x6..0
#pragma unroll
    for (int r = 0; r < 32; ++r) v[r] = ex[SW((r << 8) | tid)];
    __syncthreads();

    // RY2 q0..q4 (21..25), C0..C3, RY3 q0..q3 (42..45)
    ry_bf<4>(v, cs[21], sn[21]);
    ry_bf<3>(v, cs[22], sn[22]);
    ry_bf<2>(v, cs[23], sn[23]);
    ry_bf<1>(v, cs[24], sn[24]);
    ry_bf<0>(v, cs[25], sn[25]);
    cnot_rr<4, 3>(v);
    cnot_rr<3, 2>(v);
    cnot_rr<2, 1>(v);
    cnot_rr<1, 0>(v);
    ry_bf<4>(v, cs[42], sn[42]);
    ry_bf<3>(v, cs[43], sn[43]);
    ry_bf<2>(v, cs[44], sn[44]);
    ry_bf<1>(v, cs[45], sn[45]);

    // Exchange B -> C
#pragma unroll
    for (int r = 0; r < 32; ++r) ex[SW((r << 8) | tid)] = v[r];
    __syncthreads();
    // Layout C: regs bit j = x_{15+j}; thr bit7=x20, bits6..0=x6..0
#pragma unroll
    for (int r = 0; r < 32; ++r)
      v[r] = ex[SW(((tid >> 7) << 12) | (r << 7) | (tid & 127))];

    // RY2 q5 (p26), C4 (ctrl x16=bit1, tgt x15=bit0), RY3 q4 (p46)
    ry_bf<0>(v, cs[26], sn[26]);
    cnot_rr<1, 0>(v);
    ry_bf<1>(v, cs[46], sn[46]);

    // Store: x = x20(tid7)|x19..15(r)|x14..7(bid)|x6..0(tid&127)
#pragma unroll
    for (int r = 0; r < 32; ++r)
      st[((tid >> 7) << 20) | (r << 15) | (bid << 7) | (tid & 127)] = v[r];
  }

  grid_sync(&bar[0]);

  // ================= Phase 2 (R3 k2): block owns x20..16, x6..4 =============
  {
    const int xhi = (bid >> 3) << 16;  // x20..16
    const int xmid = (bid & 7) << 4;   // x6..4

    // Layout A: regs bit j = x_{11+j}; thr[7:4]=x10..7, thr[3:0]=x3..0
#pragma unroll
    for (int r = 0; r < 32; ++r)
      v[r] = st[xhi | (r << 11) | ((tid >> 4) << 7) | xmid | (tid & 15)];

    // RY2 q6..q9 (27..30), C5..C8, RY3 q5..q8 (47..50)
    ry_bf<3>(v, cs[27], sn[27]);
    ry_bf<2>(v, cs[28], sn[28]);
    ry_bf<1>(v, cs[29], sn[29]);
    ry_bf<0>(v, cs[30], sn[30]);
    cnot_rr<4, 3>(v);
    cnot_rr<3, 2>(v);
    cnot_rr<2, 1>(v);
    cnot_rr<1, 0>(v);
    ry_bf<4>(v, cs[47], sn[47]);
    ry_bf<3>(v, cs[48], sn[48]);
    ry_bf<2>(v, cs[49], sn[49]);
    ry_bf<1>(v, cs[50], sn[50]);

    // Exchange. Tile t[12:4]=x15..7, t[3:0]=x3..0.
#pragma unroll
    for (int r = 0; r < 32; ++r) ex[SW((r << 8) | tid)] = v[r];
    __syncthreads();
    // Layout B: regs bit j = x_{7+j}; thr[7:4]=x15..12
#pragma unroll
    for (int r = 0; r < 32; ++r)
      v[r] = ex[SW(((tid >> 4) << 9) | (r << 4) | (tid & 15))];

    // RY2 q10..q13 (31..34), C9..C12, RY3 q9..q12 (51..54)
    ry_bf<3>(v, cs[31], sn[31]);
    ry_bf<2>(v, cs[32], sn[32]);
    ry_bf<1>(v, cs[33], sn[33]);
    ry_bf<0>(v, cs[34], sn[34]);
    cnot_rr<4, 3>(v);
    cnot_rr<3, 2>(v);
    cnot_rr<2, 1>(v);
    cnot_rr<1, 0>(v);
    ry_bf<4>(v, cs[51], sn[51]);
    ry_bf<3>(v, cs[52], sn[52]);
    ry_bf<2>(v, cs[53], sn[53]);
    ry_bf<1>(v, cs[54], sn[54]);

#pragma unroll
    for (int r = 0; r < 32; ++r)
      st[xhi | ((tid >> 4) << 12) | (r << 7) | xmid | (tid & 15)] = v[r];
  }

  grid_sync(&bar[1]);

  // ================= Phase 3 (R3 k3): block owns x20..13 =============
  {
    const int xb = bid << 13;  // x20..13

    // Layout A: regs bit j = x_{3+j}; thr[7:3]=x12..8, thr[2:0]=x2..0
#pragma unroll
    for (int r = 0; r < 32; ++r)
      v[r] = st[xb | ((tid >> 3) << 8) | (r << 3) | (tid & 7)];

    // C13..C16, RY3 q13..q16 (55..58 -> bits 4..1)
    cnot_rr<4, 3>(v);
    cnot_rr<3, 2>(v);
    cnot_rr<2, 1>(v);
    cnot_rr<1, 0>(v);
    ry_bf<4>(v, cs[55], sn[55]);
    ry_bf<3>(v, cs[56], sn[56]);
    ry_bf<2>(v, cs[57], sn[57]);
    ry_bf<1>(v, cs[58], sn[58]);

    // Exchange. Tile t = x12..0.
#pragma unroll
    for (int r = 0; r < 32; ++r)
      ex[SW(((tid >> 3) << 8) | (r << 3) | (tid & 7))] = v[r];
    __syncthreads();
    // Layout B: regs bit j = x_j; thr = x12..5
#pragma unroll
    for (int r = 0; r < 32; ++r) v[r] = ex[SW((tid << 5) | r)];

    // C17..C19, RY3 q17..q20 (59..62 -> bits 3..0)
    cnot_rr<3, 2>(v);
    cnot_rr<2, 1>(v);
    cnot_rr<1, 0>(v);
    ry_bf<3>(v, cs[59], sn[59]);
    ry_bf<2>(v, cs[60], sn[60]);
    ry_bf<1>(v, cs[61], sn[61]);
    ry_bf<0>(v, cs[62], sn[62]);

    // Output: thread owns 32 consecutive elements at base.
    const int base = xb | (tid << 5);
    if (outmode == 2) {
      float4* o4 = (float4*)out;  // interleaved complex: (re,0) pairs
#pragma unroll
      for (int i = 0; i < 16; ++i)
        o4[(base >> 1) + i] = make_float4(v[2 * i], 0.0f, v[2 * i + 1], 0.0f);
    } else {
      float4* o4 = (float4*)(out + base);
#pragma unroll
      for (int j = 0; j < 8; ++j)
        o4[j] =
            make_float4(v[4 * j], v[4 * j + 1], v[4 * j + 2], v[4 * j + 3]);
    }
  }
}

extern "C" void kernel_launch(void* const* d_in, const int* in_sizes, int n_in,
                              void* d_out, int out_size, void* d_ws,
                              size_t ws_size, hipStream_t stream) {
  const float* p = (const float*)d_in[0];  // 63 fp32 params
  float* out = (float*)d_out;
  float* st = (float*)d_ws;  // 2^21 floats = 8 MB scratch state
  unsigned* bar = (unsigned*)((char*)d_ws + BAR_OFF);  // barrier counters
  const int outmode = (out_size == 2 * NSTATE) ? 2 : 1;

  // Zero the barrier counters (graph-capturable memset node; re-runs on
  // every replay, so counters are fresh each launch).
  hipMemsetAsync((void*)bar, 0, 2 * sizeof(unsigned), stream);
  fused<<<NBLK, 256, 0, stream>>>(p, st, out, outmode, bar);
}

// Round 5
// 73.034 us; speedup vs baseline: 2.0895x; 2.0895x over previous
//
#include <hip/hip_runtime.h>

// 21-qubit HEA, fp32, all-real. TWO kernels (14-bit tiles = 16384 elems,
// 512 thr x 32 regs/thread), gate windows in registers, layout switches via
// swizzled LDS exchange. No grid barriers (R4 showed device-scope barriers
// cost ~85us in cache flush/invalidate storms).
// qubit q <-> index bit (20-q). Params: RY1 q->p[q], RY2 q->p[21+q],
// RY3 q->p[42+q]. Chain C_k = CNOT(q_k, q_{k+1}) strictly in order;
// RY2 q_k before C_{k-1},C_k; RY3 q_k after. Norm==1 by unitarity.
// Init (layer1+chain1) closed form: amp(x) = prod_b f_{20-b}(y_b),
// y_b = x_b ^ x_{b+1}, y_20 = x20 (local Gray decode; verified R3).
//
// K1: tile bits {20..13} u {5..0}; block owns x12..x6 (7b).
//     A(regs x4..x0):   init, RY2 q16..q20
//     B(regs x20..x16): RY2 q0..4, C0..C3, RY3 q0..3
//     C(regs x16..x13,x5): RY2 q5,q6,q7,q15, C4..C6, RY3 q4..6
// K2: tile bits {13..0}; block owns x20..x14 (7b).
//     A(regs x13..x9): RY2 q8..11, C7..C10, RY3 q7..10
//     B(regs x9..x5):  RY2 q12..14, C11..C14, RY3 q11..14
//     C(regs x5..x1):  C15..C18, RY3 q15..18
//     D(regs x4..x0):  C19, RY3 q19,q20, output

#define NQ 21
#define NSTATE (1 << NQ)
#define SW(t) ((t) + ((t) >> 5))  // LDS anti-conflict: +1 word / 32 words

__device__ __forceinline__ float sel(const float* cs, const float* sn, int i,
                                     int bit) {
  return bit ? sn[i] : cs[i];
}

template <int BIT, int N>
__device__ __forceinline__ void ry_bf(float (&v)[N], float c, float s) {
#pragma unroll
  for (int m = 0; m < N; ++m)
    if ((m & (1 << BIT)) == 0) {
      float a = v[m], b = v[m | (1 << BIT)];
      v[m] = c * a - s * b;
      v[m | (1 << BIT)] = s * a + c * b;
    }
}

template <int CBIT, int TBIT, int N>
__device__ __forceinline__ void cnot_rr(float (&v)[N]) {
#pragma unroll
  for (int m = 0; m < N; ++m)
    if ((m & (1 << CBIT)) && !(m & (1 << TBIT))) {
      float t = v[m];
      v[m] = v[m | (1 << TBIT)];
      v[m | (1 << TBIT)] = t;
    }
}

// =========================== KERNEL 1 ===========================
__global__ __launch_bounds__(512) void k1(const float* __restrict__ p,
                                          float* __restrict__ st) {
  __shared__ float cs[63], sn[63];
  __shared__ float ex[16896];  // 16384 + 512 swizzle pad
  const int tid = threadIdx.x;  // 9 bits
  const int bid = blockIdx.x;   // 7 bits: bid_i = x_{6+i}
  if (tid < 63) {
    float h = 0.5f * p[tid];
    cs[tid] = cosf(h);
    sn[tid] = sinf(h);
  }
  __syncthreads();

  float v[32];

  // ---- Layout A: regs r_j = x_j (j=0..4); tid0 = x5; (tid>>1)_k = x_{13+k}
  {
    const int h = tid >> 1;  // 8 bits: h_k = x_{13+k}
    const int e5 = tid & 1;  // x5
    const int gb = bid ^ (bid >> 1);  // y_{6+i} = gb_i (i=0..5)
    const int u = h ^ (h >> 1);       // y_{13+k} = u_k (k=0..6)

    float Pre = sel(cs, sn, 15, e5 ^ (bid & 1));            // y5, p15
    Pre *= sel(cs, sn, 8, ((bid >> 6) ^ h) & 1);            // y12, p8
    Pre *= sel(cs, sn, 0, (h >> 7) & 1);                    // y20, p0
#pragma unroll
    for (int i = 0; i < 6; ++i) Pre *= sel(cs, sn, 14 - i, (gb >> i) & 1);
#pragma unroll
    for (int k = 0; k < 7; ++k) Pre *= sel(cs, sn, 7 - k, (u >> k) & 1);

#pragma unroll
    for (int r = 0; r < 32; ++r) {
      const int gr = r ^ (r >> 1);  // y_j = gr_j (j=0..3); y4 = gr_4 ^ x5
      float prod = Pre;
      prod *= sel(cs, sn, 20, gr & 1);
      prod *= sel(cs, sn, 19, (gr >> 1) & 1);
      prod *= sel(cs, sn, 18, (gr >> 2) & 1);
      prod *= sel(cs, sn, 17, (gr >> 3) & 1);
      prod *= sel(cs, sn, 16, ((gr >> 4) ^ e5) & 1);
      v[r] = prod;
    }
    // RY2 q16..q20 -> bits 4..0, params 37..41
    ry_bf<4>(v, cs[37], sn[37]);
    ry_bf<3>(v, cs[38], sn[38]);
    ry_bf<2>(v, cs[39], sn[39]);
    ry_bf<1>(v, cs[40], sn[40]);
    ry_bf<0>(v, cs[41], sn[41]);
  }

  // Exchange A -> B. Canonical t[13:6]=x20..13, t[5:0]=x5..0.
#pragma unroll
  for (int r = 0; r < 32; ++r) ex[SW((tid << 5) | r)] = v[r];
  __syncthreads();
  // ---- Layout B: regs r_j = x_{16+j}; tid[8:6]=x15..x13, tid[5:0]=x5..x0
#pragma unroll
  for (int r = 0; r < 32; ++r) v[r] = ex[SW((r << 9) | tid)];
  __syncthreads();

  // RY2 q0..q4 (p21..25 -> bits 20..16 = r4..r0), C0..C3, RY3 q0..3 (p42..45)
  ry_bf<4>(v, cs[21], sn[21]);
  ry_bf<3>(v, cs[22], sn[22]);
  ry_bf<2>(v, cs[23], sn[23]);
  ry_bf<1>(v, cs[24], sn[24]);
  ry_bf<0>(v, cs[25], sn[25]);
  cnot_rr<4, 3>(v);
  cnot_rr<3, 2>(v);
  cnot_rr<2, 1>(v);
  cnot_rr<1, 0>(v);
  ry_bf<4>(v, cs[42], sn[42]);
  ry_bf<3>(v, cs[43], sn[43]);
  ry_bf<2>(v, cs[44], sn[44]);
  ry_bf<1>(v, cs[45], sn[45]);

  // Exchange B -> C.
#pragma unroll
  for (int r = 0; r < 32; ++r) ex[SW((r << 9) | tid)] = v[r];
  __syncthreads();
  // ---- Layout C: r4..r1 = x16..x13, r0 = x5; tid[8:5]=x20..x17,
  //      tid[4:0]=x4..x0.  t = (tid>>5)<<10 | (r>>1)<<6 | (r&1)<<5 | tid&31
#pragma unroll
  for (int r = 0; r < 32; ++r)
    v[r] = ex[SW(((tid >> 5) << 10) | ((r >> 1) << 6) | ((r & 1) << 5) |
                 (tid & 31))];

  // RY2 q5(p26,r3), q6(p27,r2), q7(p28,r1), q15(p36,r0);
  // C4 (x16,x15)=<4,3>, C5 <3,2>, C6 <2,1>; RY3 q4(p46,r4), q5(p47,r3),
  // q6(p48,r2)
  ry_bf<3>(v, cs[26], sn[26]);
  ry_bf<2>(v, cs[27], sn[27]);
  ry_bf<1>(v, cs[28], sn[28]);
  ry_bf<0>(v, cs[36], sn[36]);
  cnot_rr<4, 3>(v);
  cnot_rr<3, 2>(v);
  cnot_rr<2, 1>(v);
  ry_bf<4>(v, cs[46], sn[46]);
  ry_bf<3>(v, cs[47], sn[47]);
  ry_bf<2>(v, cs[48], sn[48]);

  // Store: x = x20..x17 | x16..x13 | bid(x12..x6) | x5 | x4..x0
#pragma unroll
  for (int r = 0; r < 32; ++r)
    st[((tid >> 5) << 17) | ((r >> 1) << 13) | (bid << 6) | ((r & 1) << 5) |
       (tid & 31)] = v[r];
}

// =========================== KERNEL 2 ===========================
__global__ __launch_bounds__(512) void k2(const float* __restrict__ p,
                                          float* __restrict__ st,
                                          float* __restrict__ out,
                                          int outmode) {
  __shared__ float cs[63], sn[63];
  __shared__ float ex[16896];
  const int tid = threadIdx.x;  // 9 bits
  const int bid = blockIdx.x;   // 7 bits: bid_i = x_{14+i}
  if (tid < 63) {
    float h = 0.5f * p[tid];
    cs[tid] = cosf(h);
    sn[tid] = sinf(h);
  }
  __syncthreads();

  const int xb = bid << 14;
  float v[32];

  // ---- Layout A: regs r_j = x_{9+j}; tid = x8..x0. Coalesced 256B loads.
#pragma unroll
  for (int r = 0; r < 32; ++r) v[r] = st[xb | (r << 9) | tid];

  // RY2 q8(p29,r3), q9(p30,r2), q10(p31,r1), q11(p32,r0);
  // C7 (x13,x12)=<4,3>, C8 <3,2>, C9 <2,1>, C10 <1,0>;
  // RY3 q7(p49,r4), q8(p50,r3), q9(p51,r2), q10(p52,r1)
  ry_bf<3>(v, cs[29], sn[29]);
  ry_bf<2>(v, cs[30], sn[30]);
  ry_bf<1>(v, cs[31], sn[31]);
  ry_bf<0>(v, cs[32], sn[32]);
  cnot_rr<4, 3>(v);
  cnot_rr<3, 2>(v);
  cnot_rr<2, 1>(v);
  cnot_rr<1, 0>(v);
  ry_bf<4>(v, cs[49], sn[49]);
  ry_bf<3>(v, cs[50], sn[50]);
  ry_bf<2>(v, cs[51], sn[51]);
  ry_bf<1>(v, cs[52], sn[52]);

  // Exchange A -> B. Canonical t = x13..x0.
#pragma unroll
  for (int r = 0; r < 32; ++r) ex[SW((r << 9) | tid)] = v[r];
  __syncthreads();
  // ---- Layout B: regs r_j = x_{5+j}; tid[8:5]=x13..x10, tid[4:0]=x4..x0.
#pragma unroll
  for (int r = 0; r < 32; ++r)
    v[r] = ex[SW(((tid >> 5) << 10) | (r << 5) | (tid & 31))];
  __syncthreads();

  // RY2 q12(p33,r3), q13(p34,r2), q14(p35,r1);
  // C11 (x9,x8)=<4,3>, C12 <3,2>, C13 <2,1>, C14 <1,0>;
  // RY3 q11(p53,r4), q12(p54,r3), q13(p55,r2), q14(p56,r1)
  ry_bf<3>(v, cs[33], sn[33]);
  ry_bf<2>(v, cs[34], sn[34]);
  ry_bf<1>(v, cs[35], sn[35]);
  cnot_rr<4, 3>(v);
  cnot_rr<3, 2>(v);
  cnot_rr<2, 1>(v);
  cnot_rr<1, 0>(v);
  ry_bf<4>(v, cs[53], sn[53]);
  ry_bf<3>(v, cs[54], sn[54]);
  ry_bf<2>(v, cs[55], sn[55]);
  ry_bf<1>(v, cs[56], sn[56]);

  // Exchange B -> C.
#pragma unroll
  for (int r = 0; r < 32; ++r)
    ex[SW(((tid >> 5) << 10) | (r << 5) | (tid & 31))] = v[r];
  __syncthreads();
  // ---- Layout C: regs r_j = x_{1+j}; tid[8:1]=x13..x6, tid[0]=x0.
#pragma unroll
  for (int r = 0; r < 32; ++r)
    v[r] = ex[SW(((tid >> 1) << 6) | (r << 1) | (tid & 1))];
  __syncthreads();

  // C15 (x5,x4)=<4,3>, C16 <3,2>, C17 <2,1>, C18 <1,0>;
  // RY3 q15(p57,r4), q16(p58,r3), q17(p59,r2), q18(p60,r1)
  cnot_rr<4, 3>(v);
  cnot_rr<3, 2>(v);
  cnot_rr<2, 1>(v);
  cnot_rr<1, 0>(v);
  ry_bf<4>(v, cs[57], sn[57]);
  ry_bf<3>(v, cs[58], sn[58]);
  ry_bf<2>(v, cs[59], sn[59]);
  ry_bf<1>(v, cs[60], sn[60]);

  // Exchange C -> D.
#pragma unroll
  for (int r = 0; r < 32; ++r)
    ex[SW(((tid >> 1) << 6) | (r << 1) | (tid & 1))] = v[r];
  __syncthreads();
  // ---- Layout D: regs r_j = x_j; tid = x13..x5.
#pragma unroll
  for (int r = 0; r < 32; ++r) v[r] = ex[SW((tid << 5) | r)];

  // C19 (x1,x0)=<1,0>; RY3 q19(p61,bit1), q20(p62,bit0)
  cnot_rr<1, 0>(v);
  ry_bf<1>(v, cs[61], sn[61]);
  ry_bf<0>(v, cs[62], sn[62]);

  // Output: thread owns 32 consecutive elements.
  const int base = xb | (tid << 5);
  if (outmode == 2) {
    float4* o4 = (float4*)out;  // interleaved complex (re, 0)
#pragma unroll
    for (int i = 0; i < 16; ++i)
      o4[(base >> 1) + i] = make_float4(v[2 * i], 0.0f, v[2 * i + 1], 0.0f);
  } else {
    float4* o4 = (float4*)(out + base);
#pragma unroll
    for (int j = 0; j < 8; ++j)
      o4[j] = make_float4(v[4 * j], v[4 * j + 1], v[4 * j + 2], v[4 * j + 3]);
  }
}

extern "C" void kernel_launch(void* const* d_in, const int* in_sizes, int n_in,
                              void* d_out, int out_size, void* d_ws,
                              size_t ws_size, hipStream_t stream) {
  const float* p = (const float*)d_in[0];  // 63 fp32 params
  float* out = (float*)d_out;
  float* st = (float*)d_ws;  // 2^21 floats = 8 MB scratch
  const int outmode = (out_size == 2 * NSTATE) ? 2 : 1;

  k1<<<128, 512, 0, stream>>>(p, st);
  k2<<<128, 512, 0, stream>>>(p, st, out, outmode);
}